// Round 13
// baseline (387.497 us; speedup 1.0000x reference)
//
#include <hip/hip_runtime.h>
#include <stdint.h>

#define AS1 __attribute__((address_space(1)))
#define AS3 __attribute__((address_space(3)))

typedef float f32x4 __attribute__((ext_vector_type(4)));

static constexpr int NODES  = 50000;
static constexpr int EDGES  = 800000;
static constexpr int INDIM  = 512;
static constexpr int HIDDIM = 256;
static constexpr int NB_SCAN = (NODES + 255) / 256;   // 196
static constexpr int RED_BLOCKS = 64;
static constexpr int GEMM_MB256 = (NODES + 255) / 256; // 196 row-blocks (BM=256)
static constexpr int SLICE_BYTES = NODES * 64;         // 3.2 MB per column slice
static constexpr int AGGS_BLOCKS = 50000;              // 4 slices x 12500 node-blocks

// ---------------- ws layout (bytes) ----------------
static constexpr size_t OFF_PART = 0;            // f32  [4][12500][64] slice-major partials
static constexpr size_t OFF_HN   = 51200000;     // fp8  slice-major [4][50000][64]
static constexpr size_t OFF_H1P  = 76800000;     // fp8  x8 [50000][512] THEN h1p8s [4][50000][64]
static constexpr size_t OFF_W1T  = 102400000;    // fp8  [256][512]
static constexpr size_t OFF_W2T  = 102662144;    // fp8  [256][256]
static constexpr size_t OFF_DEG  = 102793216;    // i32 [50000]
static constexpr size_t OFF_FILL = 102993216;    // i32 [50000]
static constexpr size_t OFF_ROWP = 103193216;    // i32 [50001]
static constexpr size_t OFF_CSR  = 103393280;    // i32 [800000]
static constexpr size_t OFF_BSUM = 106593280;    // i32 [196]
static constexpr size_t OFF_BOFF = 106594304;    // i32 [256]
static constexpr size_t OFF_P2   = 106595840;    // f32 [64][256]
static constexpr size_t OFF_DINV = 106661376;    // f32 [50000]

__device__ __forceinline__ unsigned char f2fp8(float f) {
  int p = __builtin_amdgcn_cvt_pk_fp8_f32(f, f, 0, false);   // OCP e4m3fn
  return (unsigned char)(p & 0xff);
}
__device__ __forceinline__ void acc_fp8(float4& a, unsigned u) {
  a.x += __builtin_amdgcn_cvt_f32_fp8(u, 0);
  a.y += __builtin_amdgcn_cvt_f32_fp8(u, 1);
  a.z += __builtin_amdgcn_cvt_f32_fp8(u, 2);
  a.w += __builtin_amdgcn_cvt_f32_fp8(u, 3);
}
__device__ __forceinline__ void gload_lds8(const unsigned char* g, unsigned char* l) {
  __builtin_amdgcn_global_load_lds((const AS1 void*)g, (AS3 void*)l, 16, 0, 0);
}

// counted-wait primitives (T4)
#define WAITVM(N)  asm volatile("s_waitcnt vmcnt(" #N ")" ::: "memory")
#define HWBARRIER  { asm volatile("" ::: "memory"); __builtin_amdgcn_s_barrier(); \
                     asm volatile("" ::: "memory"); }

// ---------------- x -> fp8 (one pass) ----------------
__global__ __launch_bounds__(256) void convx8_kernel(const float* __restrict__ x,
                                                     unsigned char* __restrict__ x8) {
  size_t i = (size_t)(blockIdx.x * 256 + threadIdx.x) * 8;   // 12500*256*8 exact
  float4 v0 = *(const float4*)(x + i);
  float4 v1 = *(const float4*)(x + i + 4);
  int p0 = __builtin_amdgcn_cvt_pk_fp8_f32(v0.x, v0.y, 0, false);
  p0     = __builtin_amdgcn_cvt_pk_fp8_f32(v0.z, v0.w, p0, true);
  int p1 = __builtin_amdgcn_cvt_pk_fp8_f32(v1.x, v1.y, 0, false);
  p1     = __builtin_amdgcn_cvt_pk_fp8_f32(v1.z, v1.w, p1, true);
  *(uint2*)(x8 + i) = uint2{(unsigned)p0, (unsigned)p1};
}

// ---------------- weight transpose + fp8 + scratch zeroing (fused) ----------------
__global__ __launch_bounds__(256) void transw8_zero_kernel(const float* __restrict__ W1,
                                                           const float* __restrict__ W2,
                                                           unsigned char* __restrict__ W1T8,
                                                           unsigned char* __restrict__ W2T8,
                                                           int4* __restrict__ zreg) {
  int b = blockIdx.x, tid = threadIdx.x;
  if (b < 512) {                                    // W1T8[n][k] = fp8(W1[k][n])
    int t = b * 256 + tid; int n = t >> 9, k = t & 511;
    W1T8[t] = f2fp8(W1[k * HIDDIM + n]);
  } else if (b < 768) {
    int u = (b - 512) * 256 + tid; int n = u >> 8, k = u & 255;
    W2T8[u] = f2fp8(W2[k * HIDDIM + n]);
  } else {                                          // zero deg+fill (400000 B)
    int i = (b - 768) * 256 + tid;
    if (i < 25000) zreg[i] = int4{0, 0, 0, 0};
  }
}

// ---------------- degree histogram (inline int64-layout detect) ----------------
__global__ __launch_bounds__(256) void hist_kernel(const int* __restrict__ ei,
                                                   int* __restrict__ deg) {
  __shared__ int sflag;
  if (threadIdx.x < 64) {
    unsigned long long b = __ballot(ei[2 * threadIdx.x + 1] == 0);
    if (threadIdx.x == 0) sflag = (b == 0xFFFFFFFFFFFFFFFFull) ? 1 : 0;
  }
  __syncthreads();
  int f = sflag;
  int e = blockIdx.x * 256 + threadIdx.x;        // 3125*256 = 800000 exact
  int d = f ? ei[2 * (EDGES + e)] : ei[EDGES + e];
  atomicAdd(&deg[d], 1);
}

// ---------------- scan (3 kernels) + dinv ----------------
__global__ __launch_bounds__(256) void scan1_kernel(const int* __restrict__ deg,
                                                    int* __restrict__ rowptr,
                                                    int* __restrict__ bsum,
                                                    float* __restrict__ dinv) {
  __shared__ int s[256];
  int t = threadIdx.x, i = blockIdx.x * 256 + t;
  int v = (i < NODES) ? deg[i] : 0;
  if (i < NODES) dinv[i] = rsqrtf((float)(v + 1));   // +1 self-loop
  s[t] = v; __syncthreads();
  for (int off = 1; off < 256; off <<= 1) {
    int x = (t >= off) ? s[t - off] : 0;
    __syncthreads(); s[t] += x; __syncthreads();
  }
  if (i < NODES) rowptr[i] = s[t] - v;
  if (t == 255) bsum[blockIdx.x] = s[255];
}
__global__ __launch_bounds__(256) void scan2_kernel(const int* __restrict__ bsum,
                                                    int* __restrict__ boff,
                                                    int* __restrict__ rowptrN) {
  __shared__ int s[256];
  int t = threadIdx.x;
  int v = (t < NB_SCAN) ? bsum[t] : 0;
  s[t] = v; __syncthreads();
  for (int off = 1; off < 256; off <<= 1) {
    int x = (t >= off) ? s[t - off] : 0;
    __syncthreads(); s[t] += x; __syncthreads();
  }
  if (t < NB_SCAN) boff[t] = s[t] - v;
  if (t == 255) *rowptrN = s[255];
}
__global__ __launch_bounds__(256) void scan3_kernel(int* __restrict__ rowptr,
                                                    const int* __restrict__ boff) {
  int i = blockIdx.x * 256 + threadIdx.x;
  if (i < NODES) rowptr[i] += boff[blockIdx.x];
}

// ---------------- CSR fill (inline detect) ----------------
__global__ __launch_bounds__(256) void fill_kernel(const int* __restrict__ ei,
                                                   const int* __restrict__ rowptr,
                                                   int* __restrict__ fill,
                                                   int* __restrict__ csr) {
  __shared__ int sflag;
  if (threadIdx.x < 64) {
    unsigned long long b = __ballot(ei[2 * threadIdx.x + 1] == 0);
    if (threadIdx.x == 0) sflag = (b == 0xFFFFFFFFFFFFFFFFull) ? 1 : 0;
  }
  __syncthreads();
  int f = sflag;
  int e = blockIdx.x * 256 + threadIdx.x;
  int s, d;
  if (f) { s = ei[2 * e]; d = ei[2 * (EDGES + e)]; }
  else   { s = ei[e];     d = ei[EDGES + e]; }
  int p = atomicAdd(&fill[d], 1);
  csr[rowptr[d] + p] = s;
}

// ---------------- GEMM: fp8 memory + native fp8 MFMA. BM=BN=256, BK=64 ----
// Output written SLICE-MAJOR: Cn8s[slice=col>>6][node][col&63] so each XCD's
// agg gather footprint is a contiguous 3.2MB (< 4MB L2). ASLICED selects the
// A-source layout (gemm2 reads the sliced h1p8; one K-step == one slice block).
template<int K, bool ASLICED>
__global__ __launch_bounds__(512, 2) void gemm_fp8_kernel(const unsigned char* __restrict__ A8,
                                                          const unsigned char* __restrict__ BT8,
                                                          const float* __restrict__ dinv,
                                                          unsigned char* __restrict__ Cn8s) {
  constexpr int NSTEP = K / 64;
  __shared__ unsigned char As[2][256 * 64];    // 16 KB per buf
  __shared__ unsigned char Bs[2][256 * 64];    // 16 KB per buf (total 64 KB)
  const int tid = threadIdx.x, wave = tid >> 6, lane = tid & 63;
  const int fr = lane & 15, q = lane >> 4;
  const int wr = wave >> 2, wc = wave & 3;     // 2m x 4n
  const int m0 = blockIdx.x * 256;

  const int srl0 = lane >> 2, sch = lane & 3;  // staging: (row lane>>2, 16B grp lane&3)

  f32x4 acc[8][4] = {};

#define STAGE_A(buf, kb)                                                      \
  {                                                                           \
    _Pragma("unroll")                                                         \
    for (int c = 0; c < 2; ++c) {                                             \
      int rl = (wave * 2 + c) * 16 + srl0;                                    \
      int gr = m0 + rl; if (gr > NODES - 1) gr = NODES - 1;                   \
      const unsigned char* sp;                                                \
      if constexpr (ASLICED)                                                  \
        sp = A8 + (size_t)((kb) >> 6) * SLICE_BYTES + (size_t)gr * 64 +       \
             ((sch ^ (rl & 3)) << 4);                                         \
      else                                                                    \
        sp = A8 + (size_t)gr * K + (kb) + ((sch ^ (rl & 3)) << 4);            \
      gload_lds8(sp, &As[buf][(wave * 2 + c) * 1024]);                        \
    }                                                                         \
  }
#define STAGE_B(buf, kb)                                                      \
  {                                                                           \
    _Pragma("unroll")                                                         \
    for (int c = 0; c < 2; ++c) {                                             \
      int rl = (wave * 2 + c) * 16 + srl0;                                    \
      const unsigned char* sp = BT8 + (size_t)rl * K + (kb) +                 \
                                ((sch ^ (rl & 3)) << 4);                      \
      gload_lds8(sp, &Bs[buf][(wave * 2 + c) * 1024]);                        \
    }                                                                         \
  }

  // ---- prologue: tile 0 into buf 0 ----
  STAGE_A(0, 0);
  STAGE_B(0, 0);

  for (int t = 0; t < NSTEP; ++t) {
    const int cur = t & 1, nxt = cur ^ 1;
    if (t + 1 < NSTEP) {
      const int kb1 = (t + 1) * 64;
      STAGE_A(nxt, kb1);
      STAGE_B(nxt, kb1);
      WAITVM(4);                                // tile-t done; t+1 in flight
    } else {
      WAITVM(0);
    }
    HWBARRIER;

#pragma unroll
    for (int s = 0; s < 2; ++s) {               // two K=32 slabs per step
      long af[8], bq[4];
#pragma unroll
      for (int m = 0; m < 8; ++m) {
        int row = wr * 128 + m * 16 + fr;
        int cch = s * 2 + (q >> 1);
        af[m] = *(const long*)
            &As[cur][row * 64 + ((cch ^ (row & 3)) << 4) + (q & 1) * 8];
      }
#pragma unroll
      for (int n = 0; n < 4; ++n) {
        int row = wc * 64 + n * 16 + fr;
        int cch = s * 2 + (q >> 1);
        bq[n] = *(const long*)
            &Bs[cur][row * 64 + ((cch ^ (row & 3)) << 4) + (q & 1) * 8];
      }
#pragma unroll
      for (int m = 0; m < 8; ++m)
#pragma unroll
        for (int n = 0; n < 4; ++n)
          acc[m][n] = __builtin_amdgcn_mfma_f32_16x16x32_fp8_fp8(af[m], bq[n], acc[m][n], 0, 0, 0);
    }
    HWBARRIER;
  }
#undef STAGE_A
#undef STAGE_B

  // epilogue: C/D layout col=lane&15, row=q*4+reg; write fp8 SLICE-MAJOR (slice=wc)
  const int rq = q * 4;
#pragma unroll
  for (int m = 0; m < 8; ++m) {
    int rbase = m0 + wr * 128 + m * 16 + rq;
#pragma unroll
    for (int r = 0; r < 4; ++r) {
      int grow = rbase + r;
      if (grow < NODES) {
        float dv = dinv[grow];
#pragma unroll
        for (int n = 0; n < 4; ++n) {
          Cn8s[(size_t)wc * SLICE_BYTES + (size_t)grow * 64 + n * 16 + fr] =
              f2fp8(acc[m][n][r] * dv);
        }
      }
    }
  }
}

// ---------------- slice-local aggregation (XCD-pinned column slices) ----------------
// Grid 50000 = 8 * 6250: blockIdx%8 -> XCD (heuristic). XCD x handles slice x&3;
// its gather footprint = one contiguous 3.2MB slice block (< 4MB L2-resident).
// Wave = one node; 16-lane group per item (4 items per wave-load, 64B each);
// exec-masked loads (no wasted tail traffic); unroll-8 for MLP.
template<bool WRITE8>
__global__ __launch_bounds__(256) void aggs_kernel(const unsigned char* __restrict__ hn8s,
                                                   const float* __restrict__ dinv,
                                                   const int* __restrict__ rowptr,
                                                   const int* __restrict__ csr,
                                                   const float* __restrict__ bias,
                                                   unsigned char* __restrict__ out8s,
                                                   float* __restrict__ part) {
  __shared__ float sm[4][64];
  const int b = blockIdx.x;
  const int slice = b & 3, half = (b >> 2) & 1, idx = b >> 3;   // 50000 = 8*6250 exact
  const int wave = threadIdx.x >> 6, lane = threadIdx.x & 63;
  const int g = lane >> 4, c4 = lane & 15;
  const int nb = half * 6250 + idx;          // node-block 0..12499
  const int node = nb * 4 + wave;
  const unsigned char* base = hn8s + (size_t)slice * SLICE_BYTES;
  const int e0 = rowptr[node], e1 = rowptr[node + 1];
  const int items = e1 - e0 + 1;             // self-loop is item 0
  float4 A{0.f, 0.f, 0.f, 0.f}, Bv{0.f, 0.f, 0.f, 0.f};
  for (int it = 0; it < items; it += 8) {
    int i0 = it + g, i1 = it + 4 + g;
    unsigned v0 = 0, v1 = 0;
    if (i0 < items) {
      int row = (i0 == 0) ? node : csr[e0 + i0 - 1];
      v0 = *(const unsigned*)(base + (size_t)row * 64 + c4 * 4);
    }
    if (i1 < items) {
      int row = csr[e0 + i1 - 1];            // i1 >= 4 > 0 always
      v1 = *(const unsigned*)(base + (size_t)row * 64 + c4 * 4);
    }
    acc_fp8(A, v0); acc_fp8(Bv, v1);
  }
  A.x += Bv.x; A.y += Bv.y; A.z += Bv.z; A.w += Bv.w;
  A.x += __shfl_down(A.x, 32); A.y += __shfl_down(A.y, 32);
  A.z += __shfl_down(A.z, 32); A.w += __shfl_down(A.w, 32);
  A.x += __shfl_down(A.x, 16); A.y += __shfl_down(A.y, 16);
  A.z += __shfl_down(A.z, 16); A.w += __shfl_down(A.w, 16);
  if (lane < 16) {
    float di = dinv[node];
    const float* bp = bias + slice * 64 + c4 * 4;
    float r0 = fmaxf(fmaf(di, A.x, bp[0]), 0.f);
    float r1 = fmaxf(fmaf(di, A.y, bp[1]), 0.f);
    float r2 = fmaxf(fmaf(di, A.z, bp[2]), 0.f);
    float r3 = fmaxf(fmaf(di, A.w, bp[3]), 0.f);
    if constexpr (WRITE8) {
      int p = __builtin_amdgcn_cvt_pk_fp8_f32(r0, r1, 0, false);
      p     = __builtin_amdgcn_cvt_pk_fp8_f32(r2, r3, p, true);
      *(unsigned*)(out8s + (size_t)slice * SLICE_BYTES + (size_t)node * 64 + c4 * 4) = (unsigned)p;
    } else {
      *(float4*)&sm[wave][c4 * 4] = float4{r0, r1, r2, r3};
    }
  }
  if constexpr (!WRITE8) {
    __syncthreads();
    int t = threadIdx.x;
    if (t < 64)
      part[((size_t)slice * 12500 + nb) * 64 + t] =
          sm[0][t] + sm[1][t] + sm[2][t] + sm[3][t];
  }
}

// ---------------- readout ----------------
__global__ __launch_bounds__(256) void reduce2_kernel(const float* __restrict__ part,
                                                      float* __restrict__ p2) {
  int t = threadIdx.x, b = blockIdx.x;              // 64 blocks
  int slice = t >> 6, c = t & 63;                   // global col = slice*64+c = t
  float s = 0.f;
  for (int nb = b; nb < 12500; nb += RED_BLOCKS)
    s += part[((size_t)slice * 12500 + nb) * 64 + c];
  p2[b * 256 + t] = s;
}
__global__ __launch_bounds__(256) void final_kernel(const float* __restrict__ p2,
                                                    const float* __restrict__ Wfc,
                                                    const float* __restrict__ bfc,
                                                    float* __restrict__ out) {
  __shared__ float red[256];
  int t = threadIdx.x;
  float s = 0.f;
  for (int b = 0; b < RED_BLOCKS; ++b) s += p2[b * 256 + t];
  float g = s * (1.0f / (float)NODES);
  red[t] = g * Wfc[t];
  __syncthreads();
  for (int off = 128; off > 0; off >>= 1) {
    if (t < off) red[t] += red[t + off];
    __syncthreads();
  }
  if (t == 0) {
    float z = red[0] + bfc[0];
    out[0] = 1.0f / (1.0f + expf(-z));
  }
}

// ---------------- launch ----------------
extern "C" void kernel_launch(void* const* d_in, const int* in_sizes, int n_in,
                              void* d_out, int out_size, void* d_ws, size_t ws_size,
                              hipStream_t stream) {
  (void)in_sizes; (void)n_in; (void)out_size; (void)ws_size;
  const float* x   = (const float*)d_in[0];
  const int*   ei  = (const int*)d_in[1];
  const float* W1  = (const float*)d_in[2];
  const float* b1  = (const float*)d_in[3];
  const float* W2  = (const float*)d_in[4];
  const float* b2  = (const float*)d_in[5];
  const float* Wfc = (const float*)d_in[6];
  const float* bfc = (const float*)d_in[7];
  float* out = (float*)d_out;
  char* ws = (char*)d_ws;

  unsigned char*  hn8s  = (unsigned char*)(ws + OFF_HN);    // slice-major [4][50000][64]
  unsigned char*  x8    = (unsigned char*)(ws + OFF_H1P);   // row-major, dead after gemm1
  unsigned char*  h1p8s = (unsigned char*)(ws + OFF_H1P);   // slice-major, after agg1
  unsigned char*  w1t8  = (unsigned char*)(ws + OFF_W1T);
  unsigned char*  w2t8  = (unsigned char*)(ws + OFF_W2T);
  int*   deg    = (int*)(ws + OFF_DEG);
  int*   fill   = (int*)(ws + OFF_FILL);
  int*   rowptr = (int*)(ws + OFF_ROWP);
  int*   csr    = (int*)(ws + OFF_CSR);
  int*   bsum   = (int*)(ws + OFF_BSUM);
  int*   boff   = (int*)(ws + OFF_BOFF);
  float* part   = (float*)(ws + OFF_PART);
  float* p2     = (float*)(ws + OFF_P2);
  float* dinv   = (float*)(ws + OFF_DINV);

  transw8_zero_kernel<<<866, 256, 0, stream>>>(W1, W2, w1t8, w2t8, (int4*)deg);
  hist_kernel<<<EDGES / 256, 256, 0, stream>>>(ei, deg);
  scan1_kernel<<<NB_SCAN, 256, 0, stream>>>(deg, rowptr, bsum, dinv);
  scan2_kernel<<<1, 256, 0, stream>>>(bsum, boff, rowptr + NODES);
  scan3_kernel<<<NB_SCAN, 256, 0, stream>>>(rowptr, boff);
  fill_kernel<<<EDGES / 256, 256, 0, stream>>>(ei, rowptr, fill, csr);
  convx8_kernel<<<NODES * INDIM / (256 * 8), 256, 0, stream>>>(x, x8);

  gemm_fp8_kernel<INDIM, false><<<GEMM_MB256, 512, 0, stream>>>(x8, w1t8, dinv, hn8s);
  aggs_kernel<true><<<AGGS_BLOCKS, 256, 0, stream>>>(hn8s, dinv, rowptr, csr, b1, h1p8s, nullptr);
  gemm_fp8_kernel<HIDDIM, true><<<GEMM_MB256, 512, 0, stream>>>(h1p8s, w2t8, dinv, hn8s);
  aggs_kernel<false><<<AGGS_BLOCKS, 256, 0, stream>>>(hn8s, dinv, rowptr, csr, b2, nullptr, part);
  reduce2_kernel<<<RED_BLOCKS, 256, 0, stream>>>(part, p2);
  final_kernel<<<1, 256, 0, stream>>>(p2, Wfc, bfc, out);
}

// Round 14
// 342.729 us; speedup vs baseline: 1.1306x; 1.1306x over previous
//
#include <hip/hip_runtime.h>
#include <stdint.h>

#define AS1 __attribute__((address_space(1)))
#define AS3 __attribute__((address_space(3)))

typedef float f32x4 __attribute__((ext_vector_type(4)));

static constexpr int NODES  = 50000;
static constexpr int EDGES  = 800000;
static constexpr int INDIM  = 512;
static constexpr int HIDDIM = 256;
static constexpr int NB_SCAN = (NODES + 255) / 256;   // 196
static constexpr int RED_BLOCKS = 64;
static constexpr int GEMM_MB256 = (NODES + 255) / 256; // 196 row-blocks (BM=256)
static constexpr int ZROW = 50000;                     // dedicated zero row
static constexpr int SLICE_ROWS = 50016;               // 50001 rounded up
static constexpr size_t SLICE_STRIDE_B = (size_t)SLICE_ROWS * 64;  // 3,201,024
static constexpr int AGGS_BLOCKS = 50000;              // 4 slices x 12500 node-blocks

// ---------------- ws layout (bytes) ----------------
static constexpr size_t OFF_PART   = 0;          // f32 [4][12500][64] (12.8 MB)
static constexpr size_t OFF_PADCSR = 13000000;   // i32 [<=1.4M] padded adjacency
static constexpr size_t OFF_POFF   = 19000000;   // i32 [50001]
static constexpr size_t OFF_HN     = 51200000;   // fp8 slice-major [4][SLICE_ROWS][64]
static constexpr size_t OFF_H1P    = 76800000;   // fp8 x8 [50000][512] THEN h1p8s
static constexpr size_t OFF_W1T    = 102400000;  // fp8 [256][512]
static constexpr size_t OFF_W2T    = 102662144;  // fp8 [256][256]
static constexpr size_t OFF_DEG    = 102793216;  // i32 [50000]
static constexpr size_t OFF_FILL   = 102993216;  // i32 [50000]
static constexpr size_t OFF_BSUM   = 106593280;  // i32 [196]
static constexpr size_t OFF_BOFF   = 106594304;  // i32 [256]
static constexpr size_t OFF_P2     = 106595840;  // f32 [64][256]
static constexpr size_t OFF_DINV   = 106661376;  // f32 [50000]

__device__ __forceinline__ unsigned char f2fp8(float f) {
  int p = __builtin_amdgcn_cvt_pk_fp8_f32(f, f, 0, false);   // OCP e4m3fn
  return (unsigned char)(p & 0xff);
}
__device__ __forceinline__ void acc_fp8(float4& a, unsigned u) {
  a.x += __builtin_amdgcn_cvt_f32_fp8(u, 0);
  a.y += __builtin_amdgcn_cvt_f32_fp8(u, 1);
  a.z += __builtin_amdgcn_cvt_f32_fp8(u, 2);
  a.w += __builtin_amdgcn_cvt_f32_fp8(u, 3);
}
__device__ __forceinline__ void gload_lds8(const unsigned char* g, unsigned char* l) {
  __builtin_amdgcn_global_load_lds((const AS1 void*)g, (AS3 void*)l, 16, 0, 0);
}

// counted-wait primitives (T4)
#define WAITVM(N)  asm volatile("s_waitcnt vmcnt(" #N ")" ::: "memory")
#define HWBARRIER  { asm volatile("" ::: "memory"); __builtin_amdgcn_s_barrier(); \
                     asm volatile("" ::: "memory"); }

// ---------------- x -> fp8 (one pass) ----------------
__global__ __launch_bounds__(256) void convx8_kernel(const float* __restrict__ x,
                                                     unsigned char* __restrict__ x8) {
  size_t i = (size_t)(blockIdx.x * 256 + threadIdx.x) * 8;   // 12500*256*8 exact
  float4 v0 = *(const float4*)(x + i);
  float4 v1 = *(const float4*)(x + i + 4);
  int p0 = __builtin_amdgcn_cvt_pk_fp8_f32(v0.x, v0.y, 0, false);
  p0     = __builtin_amdgcn_cvt_pk_fp8_f32(v0.z, v0.w, p0, true);
  int p1 = __builtin_amdgcn_cvt_pk_fp8_f32(v1.x, v1.y, 0, false);
  p1     = __builtin_amdgcn_cvt_pk_fp8_f32(v1.z, v1.w, p1, true);
  *(uint2*)(x8 + i) = uint2{(unsigned)p0, (unsigned)p1};
}

// ------- weight transpose + fp8 + zero deg/fill + zero ZROW (fused) -------
__global__ __launch_bounds__(256) void transw8_zero_kernel(const float* __restrict__ W1,
                                                           const float* __restrict__ W2,
                                                           unsigned char* __restrict__ W1T8,
                                                           unsigned char* __restrict__ W2T8,
                                                           int4* __restrict__ zreg,
                                                           unsigned char* __restrict__ hn8s) {
  int b = blockIdx.x, tid = threadIdx.x;
  if (b < 512) {                                    // W1T8[n][k] = fp8(W1[k][n])
    int t = b * 256 + tid; int n = t >> 9, k = t & 511;
    W1T8[t] = f2fp8(W1[k * HIDDIM + n]);
  } else if (b < 768) {
    int u = (b - 512) * 256 + tid; int n = u >> 8, k = u & 255;
    W2T8[u] = f2fp8(W2[k * HIDDIM + n]);
  } else if (b < 866) {                             // zero deg+fill (400000 B)
    int i = (b - 768) * 256 + tid;
    if (i < 25000) zreg[i] = int4{0, 0, 0, 0};
  } else {                                          // zero ZROW in all 4 slices
    int slice = tid >> 6, col = tid & 63;
    hn8s[(size_t)slice * SLICE_STRIDE_B + (size_t)ZROW * 64 + col] = 0;
  }
}

// ---------------- degree histogram (inline int64-layout detect) ----------------
__global__ __launch_bounds__(256) void hist_kernel(const int* __restrict__ ei,
                                                   int* __restrict__ deg) {
  __shared__ int sflag;
  if (threadIdx.x < 64) {
    unsigned long long b = __ballot(ei[2 * threadIdx.x + 1] == 0);
    if (threadIdx.x == 0) sflag = (b == 0xFFFFFFFFFFFFFFFFull) ? 1 : 0;
  }
  __syncthreads();
  int f = sflag;
  int e = blockIdx.x * 256 + threadIdx.x;        // 3125*256 = 800000 exact
  int d = f ? ei[2 * (EDGES + e)] : ei[EDGES + e];
  atomicAdd(&deg[d], 1);
}

// -------- scan over PADDED degree (pdeg = (deg+8)&~7) + dinv --------
__global__ __launch_bounds__(256) void scan1_kernel(const int* __restrict__ deg,
                                                    int* __restrict__ poff,
                                                    int* __restrict__ bsum,
                                                    float* __restrict__ dinv) {
  __shared__ int s[256];
  int t = threadIdx.x, i = blockIdx.x * 256 + t;
  int d = (i < NODES) ? deg[i] : 0;
  int v = (i < NODES) ? ((d + 8) & ~7) : 0;          // self + pads to mult of 8
  if (i < NODES) dinv[i] = rsqrtf((float)(d + 1));   // +1 self-loop
  s[t] = v; __syncthreads();
  for (int off = 1; off < 256; off <<= 1) {
    int x = (t >= off) ? s[t - off] : 0;
    __syncthreads(); s[t] += x; __syncthreads();
  }
  if (i < NODES) poff[i] = s[t] - v;
  if (t == 255) bsum[blockIdx.x] = s[255];
}
__global__ __launch_bounds__(256) void scan2_kernel(const int* __restrict__ bsum,
                                                    int* __restrict__ boff,
                                                    int* __restrict__ poffN) {
  __shared__ int s[256];
  int t = threadIdx.x;
  int v = (t < NB_SCAN) ? bsum[t] : 0;
  s[t] = v; __syncthreads();
  for (int off = 1; off < 256; off <<= 1) {
    int x = (t >= off) ? s[t - off] : 0;
    __syncthreads(); s[t] += x; __syncthreads();
  }
  if (t < NB_SCAN) boff[t] = s[t] - v;
  if (t == 255) *poffN = s[255];
}
__global__ __launch_bounds__(256) void scan3_kernel(int* __restrict__ poff,
                                                    const int* __restrict__ boff) {
  int i = blockIdx.x * 256 + threadIdx.x;
  if (i < NODES) poff[i] += boff[blockIdx.x];
}

// -------- pad-fill: slot0 = self, tail slots = ZROW --------
__global__ __launch_bounds__(256) void padfill_kernel(const int* __restrict__ deg,
                                                      const int* __restrict__ poff,
                                                      int* __restrict__ padcsr) {
  int i = blockIdx.x * 256 + threadIdx.x;
  if (i < NODES) {
    int d = deg[i], b0 = poff[i], pd = (d + 8) & ~7;
    padcsr[b0] = i;
    for (int s = d + 1; s < pd; ++s) padcsr[b0 + s] = ZROW;
  }
}

// ---------------- CSR fill into padded slots (inline detect) ----------------
__global__ __launch_bounds__(256) void fill_kernel(const int* __restrict__ ei,
                                                   const int* __restrict__ poff,
                                                   int* __restrict__ fill,
                                                   int* __restrict__ padcsr) {
  __shared__ int sflag;
  if (threadIdx.x < 64) {
    unsigned long long b = __ballot(ei[2 * threadIdx.x + 1] == 0);
    if (threadIdx.x == 0) sflag = (b == 0xFFFFFFFFFFFFFFFFull) ? 1 : 0;
  }
  __syncthreads();
  int f = sflag;
  int e = blockIdx.x * 256 + threadIdx.x;
  int s, d;
  if (f) { s = ei[2 * e]; d = ei[2 * (EDGES + e)]; }
  else   { s = ei[e];     d = ei[EDGES + e]; }
  int p = atomicAdd(&fill[d], 1);
  padcsr[poff[d] + 1 + p] = s;
}

// ---------------- GEMM: fp8 memory + native fp8 MFMA. BM=BN=256, BK=64 ----
// Output slice-major: Cn8s[slice=col>>6][node][col&63], stride SLICE_STRIDE_B.
template<int K, bool ASLICED>
__global__ __launch_bounds__(512, 2) void gemm_fp8_kernel(const unsigned char* __restrict__ A8,
                                                          const unsigned char* __restrict__ BT8,
                                                          const float* __restrict__ dinv,
                                                          unsigned char* __restrict__ Cn8s) {
  constexpr int NSTEP = K / 64;
  __shared__ unsigned char As[2][256 * 64];    // 16 KB per buf
  __shared__ unsigned char Bs[2][256 * 64];    // 16 KB per buf (total 64 KB)
  const int tid = threadIdx.x, wave = tid >> 6, lane = tid & 63;
  const int fr = lane & 15, q = lane >> 4;
  const int wr = wave >> 2, wc = wave & 3;     // 2m x 4n
  const int m0 = blockIdx.x * 256;

  const int srl0 = lane >> 2, sch = lane & 3;  // staging: (row lane>>2, 16B grp lane&3)

  f32x4 acc[8][4] = {};

#define STAGE_A(buf, kb)                                                      \
  {                                                                           \
    _Pragma("unroll")                                                         \
    for (int c = 0; c < 2; ++c) {                                             \
      int rl = (wave * 2 + c) * 16 + srl0;                                    \
      int gr = m0 + rl; if (gr > NODES - 1) gr = NODES - 1;                   \
      const unsigned char* sp;                                                \
      if constexpr (ASLICED)                                                  \
        sp = A8 + (size_t)((kb) >> 6) * SLICE_STRIDE_B + (size_t)gr * 64 +    \
             ((sch ^ (rl & 3)) << 4);                                         \
      else                                                                    \
        sp = A8 + (size_t)gr * K + (kb) + ((sch ^ (rl & 3)) << 4);            \
      gload_lds8(sp, &As[buf][(wave * 2 + c) * 1024]);                        \
    }                                                                         \
  }
#define STAGE_B(buf, kb)                                                      \
  {                                                                           \
    _Pragma("unroll")                                                         \
    for (int c = 0; c < 2; ++c) {                                             \
      int rl = (wave * 2 + c) * 16 + srl0;                                    \
      const unsigned char* sp = BT8 + (size_t)rl * K + (kb) +                 \
                                ((sch ^ (rl & 3)) << 4);                      \
      gload_lds8(sp, &Bs[buf][(wave * 2 + c) * 1024]);                        \
    }                                                                         \
  }

  // ---- prologue: tile 0 into buf 0 ----
  STAGE_A(0, 0);
  STAGE_B(0, 0);

  for (int t = 0; t < NSTEP; ++t) {
    const int cur = t & 1, nxt = cur ^ 1;
    if (t + 1 < NSTEP) {
      const int kb1 = (t + 1) * 64;
      STAGE_A(nxt, kb1);
      STAGE_B(nxt, kb1);
      WAITVM(4);                                // tile-t done; t+1 in flight
    } else {
      WAITVM(0);
    }
    HWBARRIER;

#pragma unroll
    for (int s = 0; s < 2; ++s) {               // two K=32 slabs per step
      long af[8], bq[4];
#pragma unroll
      for (int m = 0; m < 8; ++m) {
        int row = wr * 128 + m * 16 + fr;
        int cch = s * 2 + (q >> 1);
        af[m] = *(const long*)
            &As[cur][row * 64 + ((cch ^ (row & 3)) << 4) + (q & 1) * 8];
      }
#pragma unroll
      for (int n = 0; n < 4; ++n) {
        int row = wc * 64 + n * 16 + fr;
        int cch = s * 2 + (q >> 1);
        bq[n] = *(const long*)
            &Bs[cur][row * 64 + ((cch ^ (row & 3)) << 4) + (q & 1) * 8];
      }
#pragma unroll
      for (int m = 0; m < 8; ++m)
#pragma unroll
        for (int n = 0; n < 4; ++n)
          acc[m][n] = __builtin_amdgcn_mfma_f32_16x16x32_fp8_fp8(af[m], bq[n], acc[m][n], 0, 0, 0);
    }
    HWBARRIER;
  }
#undef STAGE_A
#undef STAGE_B

  // epilogue: C/D layout col=lane&15, row=q*4+reg; write fp8 slice-major (slice=wc)
  const int rq = q * 4;
#pragma unroll
  for (int m = 0; m < 8; ++m) {
    int rbase = m0 + wr * 128 + m * 16 + rq;
#pragma unroll
    for (int r = 0; r < 4; ++r) {
      int grow = rbase + r;
      if (grow < NODES) {
        float dv = dinv[grow];
#pragma unroll
        for (int n = 0; n < 4; ++n) {
          Cn8s[(size_t)wc * SLICE_STRIDE_B + (size_t)grow * 64 + n * 16 + fr] =
              f2fp8(acc[m][n][r] * dv);
        }
      }
    }
  }
}

// ------- slice-local aggregation: padded adjacency, branch-free loop -------
// Grid 50000 = 8 * 6250: blockIdx%8 -> XCD; XCD x owns slice x&3 (3.2MB < L2).
// Wave = one node-slice; 16-lane group per item; items = multiple of 8 (padded
// with ZROW which is all zeros) -> NO divergence, NO compares, 4 idx + 4
// payload loads in flight per step-16 iteration.
template<bool WRITE8>
__global__ __launch_bounds__(256) void aggs_kernel(const unsigned char* __restrict__ hn8s,
                                                   const float* __restrict__ dinv,
                                                   const int* __restrict__ poff,
                                                   const int* __restrict__ padcsr,
                                                   const float* __restrict__ bias,
                                                   unsigned char* __restrict__ out8s,
                                                   float* __restrict__ part) {
  __shared__ float sm[4][64];
  const int b = blockIdx.x;
  const int slice = b & 3, half = (b >> 2) & 1, idx = b >> 3;   // 50000 = 8*6250
  const int wave = threadIdx.x >> 6, lane = threadIdx.x & 63;
  const int g = lane >> 4, c4 = lane & 15;
  const int nb = half * 6250 + idx;          // node-block 0..12499
  const int node = nb * 4 + wave;
  const unsigned char* base = hn8s + (size_t)slice * SLICE_STRIDE_B;
  const int p0 = poff[node], p1 = poff[node + 1];
  const int items = p1 - p0;                 // multiple of 8, >= 8
  const int* pc = padcsr + p0;
  float4 A{0.f, 0.f, 0.f, 0.f}, Bv{0.f, 0.f, 0.f, 0.f};
  int it = 0;
  for (; it + 16 <= items; it += 16) {
    int r0 = pc[it + g],     r1 = pc[it + 4 + g];
    int r2 = pc[it + 8 + g], r3 = pc[it + 12 + g];
    unsigned v0 = *(const unsigned*)(base + (size_t)r0 * 64 + c4 * 4);
    unsigned v1 = *(const unsigned*)(base + (size_t)r1 * 64 + c4 * 4);
    unsigned v2 = *(const unsigned*)(base + (size_t)r2 * 64 + c4 * 4);
    unsigned v3 = *(const unsigned*)(base + (size_t)r3 * 64 + c4 * 4);
    acc_fp8(A, v0); acc_fp8(Bv, v1); acc_fp8(A, v2); acc_fp8(Bv, v3);
  }
  if (it < items) {                          // exactly 8 remain (wave-uniform)
    int r0 = pc[it + g], r1 = pc[it + 4 + g];
    unsigned v0 = *(const unsigned*)(base + (size_t)r0 * 64 + c4 * 4);
    unsigned v1 = *(const unsigned*)(base + (size_t)r1 * 64 + c4 * 4);
    acc_fp8(A, v0); acc_fp8(Bv, v1);
  }
  A.x += Bv.x; A.y += Bv.y; A.z += Bv.z; A.w += Bv.w;
  A.x += __shfl_down(A.x, 32); A.y += __shfl_down(A.y, 32);
  A.z += __shfl_down(A.z, 32); A.w += __shfl_down(A.w, 32);
  A.x += __shfl_down(A.x, 16); A.y += __shfl_down(A.y, 16);
  A.z += __shfl_down(A.z, 16); A.w += __shfl_down(A.w, 16);
  if (lane < 16) {
    float di = dinv[node];
    float4 bq = *(const float4*)(bias + slice * 64 + c4 * 4);
    float r0 = fmaxf(fmaf(di, A.x, bq.x), 0.f);
    float r1 = fmaxf(fmaf(di, A.y, bq.y), 0.f);
    float r2 = fmaxf(fmaf(di, A.z, bq.z), 0.f);
    float r3 = fmaxf(fmaf(di, A.w, bq.w), 0.f);
    if constexpr (WRITE8) {
      int p = __builtin_amdgcn_cvt_pk_fp8_f32(r0, r1, 0, false);
      p     = __builtin_amdgcn_cvt_pk_fp8_f32(r2, r3, p, true);
      *(unsigned*)(out8s + (size_t)slice * SLICE_STRIDE_B + (size_t)node * 64 + c4 * 4) = (unsigned)p;
    } else {
      *(float4*)&sm[wave][c4 * 4] = float4{r0, r1, r2, r3};
    }
  }
  if constexpr (!WRITE8) {
    __syncthreads();
    int t = threadIdx.x;
    if (t < 64)
      part[((size_t)slice * 12500 + nb) * 64 + t] =
          sm[0][t] + sm[1][t] + sm[2][t] + sm[3][t];
  }
}

// ---------------- readout ----------------
__global__ __launch_bounds__(256) void reduce2_kernel(const float* __restrict__ part,
                                                      float* __restrict__ p2) {
  int t = threadIdx.x, b = blockIdx.x;              // 64 blocks
  int slice = t >> 6, c = t & 63;                   // global col = slice*64+c = t
  float s = 0.f;
  for (int nb = b; nb < 12500; nb += RED_BLOCKS)
    s += part[((size_t)slice * 12500 + nb) * 64 + c];
  p2[b * 256 + t] = s;
}
__global__ __launch_bounds__(256) void final_kernel(const float* __restrict__ p2,
                                                    const float* __restrict__ Wfc,
                                                    const float* __restrict__ bfc,
                                                    float* __restrict__ out) {
  __shared__ float red[256];
  int t = threadIdx.x;
  float s = 0.f;
  for (int b = 0; b < RED_BLOCKS; ++b) s += p2[b * 256 + t];
  float g = s * (1.0f / (float)NODES);
  red[t] = g * Wfc[t];
  __syncthreads();
  for (int off = 128; off > 0; off >>= 1) {
    if (t < off) red[t] += red[t + off];
    __syncthreads();
  }
  if (t == 0) {
    float z = red[0] + bfc[0];
    out[0] = 1.0f / (1.0f + expf(-z));
  }
}

// ---------------- launch ----------------
extern "C" void kernel_launch(void* const* d_in, const int* in_sizes, int n_in,
                              void* d_out, int out_size, void* d_ws, size_t ws_size,
                              hipStream_t stream) {
  (void)in_sizes; (void)n_in; (void)out_size; (void)ws_size;
  const float* x   = (const float*)d_in[0];
  const int*   ei  = (const int*)d_in[1];
  const float* W1  = (const float*)d_in[2];
  const float* b1  = (const float*)d_in[3];
  const float* W2  = (const float*)d_in[4];
  const float* b2  = (const float*)d_in[5];
  const float* Wfc = (const float*)d_in[6];
  const float* bfc = (const float*)d_in[7];
  float* out = (float*)d_out;
  char* ws = (char*)d_ws;

  unsigned char*  hn8s  = (unsigned char*)(ws + OFF_HN);    // slice-major
  unsigned char*  x8    = (unsigned char*)(ws + OFF_H1P);   // row-major, dead after gemm1
  unsigned char*  h1p8s = (unsigned char*)(ws + OFF_H1P);   // slice-major, after agg1
  unsigned char*  w1t8  = (unsigned char*)(ws + OFF_W1T);
  unsigned char*  w2t8  = (unsigned char*)(ws + OFF_W2T);
  int*   deg    = (int*)(ws + OFF_DEG);
  int*   fill   = (int*)(ws + OFF_FILL);
  int*   poff   = (int*)(ws + OFF_POFF);
  int*   padcsr = (int*)(ws + OFF_PADCSR);
  int*   bsum   = (int*)(ws + OFF_BSUM);
  int*   boff   = (int*)(ws + OFF_BOFF);
  float* part   = (float*)(ws + OFF_PART);
  float* p2     = (float*)(ws + OFF_P2);
  float* dinv   = (float*)(ws + OFF_DINV);

  transw8_zero_kernel<<<867, 256, 0, stream>>>(W1, W2, w1t8, w2t8, (int4*)deg, hn8s);
  hist_kernel<<<EDGES / 256, 256, 0, stream>>>(ei, deg);
  scan1_kernel<<<NB_SCAN, 256, 0, stream>>>(deg, poff, bsum, dinv);
  scan2_kernel<<<1, 256, 0, stream>>>(bsum, boff, poff + NODES);
  scan3_kernel<<<NB_SCAN, 256, 0, stream>>>(poff, boff);
  padfill_kernel<<<NB_SCAN, 256, 0, stream>>>(deg, poff, padcsr);
  fill_kernel<<<EDGES / 256, 256, 0, stream>>>(ei, poff, fill, padcsr);
  convx8_kernel<<<NODES * INDIM / (256 * 8), 256, 0, stream>>>(x, x8);

  gemm_fp8_kernel<INDIM, false><<<GEMM_MB256, 512, 0, stream>>>(x8, w1t8, dinv, hn8s);
  aggs_kernel<true><<<AGGS_BLOCKS, 256, 0, stream>>>(hn8s, dinv, poff, padcsr, b1, h1p8s, nullptr);
  gemm_fp8_kernel<HIDDIM, true><<<GEMM_MB256, 512, 0, stream>>>(h1p8s, w2t8, dinv, hn8s);
  aggs_kernel<false><<<AGGS_BLOCKS, 256, 0, stream>>>(hn8s, dinv, poff, padcsr, b2, nullptr, part);
  reduce2_kernel<<<RED_BLOCKS, 256, 0, stream>>>(part, p2);
  final_kernel<<<1, 256, 0, stream>>>(p2, Wfc, bfc, out);
}